// Round 6
// baseline (345.385 us; speedup 1.0000x reference)
//
#include <hip/hip_runtime.h>
#include <cstdint>
#include <cstddef>

#define INPUT_DIM 784
#define HIDDEN    4096
#define BATCH     64
#define T_STEPS   30
#define N0 (BATCH*INPUT_DIM)   // 50176
#define N1 (BATCH*HIDDEN)      // 262144
#define M_ROWS (T_STEPS*BATCH) // 1920
#define NDIG 4
#define MB_CNT (M_ROWS/32)     // 60
#define ACH 61440              // A chunk bytes = MB_CNT*64*16
// layer 1: K=784 -> 25 data chunks, padded to KCP1=27 (mult of 3); alloc 28 B-chunks
#define KCP1 27
#define KCA1 28
// layer 2: K=4096 -> 128 chunks, padded to KCP2=129; alloc 132 B-chunks
#define KCP2 129
#define KCA2 132

typedef int v4i  __attribute__((ext_vector_type(4)));
typedef int v16i __attribute__((ext_vector_type(16)));

// ---------------- max(x) reduction (unchanged, passing) --------------------
__global__ __launch_bounds__(256) void max_kernel(const float* __restrict__ x,
                                                  unsigned* __restrict__ maxbits) {
    int i = blockIdx.x * 256 + threadIdx.x;
    float v = (i < N0) ? x[i] : 0.0f;
    #pragma unroll
    for (int off = 32; off > 0; off >>= 1)
        v = fmaxf(v, __shfl_down(v, off, 64));
    __shared__ float sm[4];
    int lane = threadIdx.x & 63;
    int wv   = threadIdx.x >> 6;
    if (lane == 0) sm[wv] = v;
    __syncthreads();
    if (threadIdx.x == 0) {
        float m = fmaxf(fmaxf(sm[0], sm[1]), fmaxf(sm[2], sm[3]));
        atomicMax(maxbits, __float_as_uint(m));
    }
}

// ---------------- layer 0 LIF (same math, passing) -> A-fragments ----------
__global__ __launch_bounds__(256) void lif0_kernel(const float* __restrict__ x,
                                                   const unsigned* __restrict__ maxbits,
                                                   uint8_t* __restrict__ AF1,
                                                   float* __restrict__ out0) {
    int j = blockIdx.x * 256 + threadIdx.x;
    int b = blockIdx.y;
    if (j >= INPUT_DIM) return;
    float mx = fmaxf(__uint_as_float(*maxbits), 1e-12f);
    float xs = __fmul_rn(__fdiv_rn(x[b * INPUT_DIM + j], mx), 16.0f);
    int kc = j >> 5;
    int lane = (b & 31) | (((j >> 4) & 1) << 5);
    size_t base = (((size_t)(kc * MB_CNT + (b >> 5)) * 64 + lane) << 4) + (j & 15);
    float v = 0.0f;
    int cnt = 0;
    #pragma unroll
    for (int t = 0; t < T_STEPS; ++t) {
        v = __fadd_rn(__fmul_rn(v, 0.99f), xs);
        int s = (v >= 0.5f) ? 1 : 0;
        cnt += s;
        v = s ? 0.0f : v;
        AF1[base + (size_t)t * 2048] = (uint8_t)s;
    }
    out0[b * INPUT_DIM + j] = (float)cnt / 30.0f;
}

// ---------------- W -> 4 digit planes, B-fragment order, single-pass -------
// Each thread extracts ALL 4 digits of its 16 elements (no redundant fp64
// conversion across waves). Block: 32 n x 128 k. Rows k >= Krows -> zeros.
__global__ __launch_bounds__(256) void digitize_kernel(const float* __restrict__ W,
                                                       int8_t* __restrict__ BF,
                                                       int Krows, int KCA, double scale) {
    __shared__ float tile[128][33];
    const int nb = blockIdx.x, kb = blockIdx.y;
    const int tid = threadIdx.x;
    #pragma unroll
    for (int p = 0; p < 4; ++p) {
        int r  = p * 32 + (tid >> 3);
        int c4 = (tid & 7) << 2;
        int k  = kb * 128 + r;
        float4 w4 = make_float4(0.f, 0.f, 0.f, 0.f);
        if (k < Krows)
            w4 = *(const float4*)&W[(size_t)k * HIDDEN + nb * 32 + c4];
        tile[r][c4]     = w4.x;
        tile[r][c4 + 1] = w4.y;
        tile[r][c4 + 2] = w4.z;
        tile[r][c4 + 3] = w4.w;
    }
    __syncthreads();
    const int kcq  = tid >> 6;        // which 32-k chunk of the 4 in this block
    const int lane = tid & 63;
    const int nl   = lane & 31;
    const int kh   = (lane >> 5) << 4;
    char dig[4][16];
    #pragma unroll
    for (int jj = 0; jj < 16; ++jj) {
        double wv = (double)tile[kcq * 32 + kh + jj][nl];
        long long q = __double2ll_rn(wv * scale);
        #pragma unroll
        for (int d = 0; d < 4; ++d) {
            int dd = (int)(((q + 128) & 255) - 128);
            q = (q - (long long)dd) >> 8;
            dig[d][jj] = (char)dd;
        }
    }
    const int kc = kb * 4 + kcq;
    #pragma unroll
    for (int d = 0; d < 4; ++d)
        *(int4*)&BF[((((size_t)nb * KCA + kc) * NDIG + d) << 10) + (lane << 4)] =
            *(int4*)&dig[d][0];
}

// ---------------- exact i8-digit streaming GEMM, depth-3 pipeline ----------
// C(1920 x 4096 f64) = A(binary) @ W. No LDS, no barriers. 3-slot register
// ring: MFMA consumes loads issued 3 iterations (~1750 SIMD-cyc) back.
// KCP % 3 == 0 via zero-padded A chunks (A=0 -> exact; junk B harmless).
// XCD swizzle: per-XCD by-window of 4 -> 4 MB B working set fits L2.
#define MFMA_GRP(s)                                                                  \
    acc[0][0] = __builtin_amdgcn_mfma_i32_32x32x32_i8(As[s][0], Bs[s][0], acc[0][0], 0, 0, 0); \
    acc[1][0] = __builtin_amdgcn_mfma_i32_32x32x32_i8(As[s][1], Bs[s][0], acc[1][0], 0, 0, 0); \
    acc[0][1] = __builtin_amdgcn_mfma_i32_32x32x32_i8(As[s][0], Bs[s][1], acc[0][1], 0, 0, 0); \
    acc[1][1] = __builtin_amdgcn_mfma_i32_32x32x32_i8(As[s][1], Bs[s][1], acc[1][1], 0, 0, 0); \
    acc[0][2] = __builtin_amdgcn_mfma_i32_32x32x32_i8(As[s][0], Bs[s][2], acc[0][2], 0, 0, 0); \
    acc[1][2] = __builtin_amdgcn_mfma_i32_32x32x32_i8(As[s][1], Bs[s][2], acc[1][2], 0, 0, 0); \
    acc[0][3] = __builtin_amdgcn_mfma_i32_32x32x32_i8(As[s][0], Bs[s][3], acc[0][3], 0, 0, 0); \
    acc[1][3] = __builtin_amdgcn_mfma_i32_32x32x32_i8(As[s][1], Bs[s][3], acc[1][3], 0, 0, 0)

#define LOADC(s)                                                        \
    Bs[s][0] = *(const v4i*)bp;          Bs[s][1] = *(const v4i*)(bp + 1024); \
    Bs[s][2] = *(const v4i*)(bp + 2048); Bs[s][3] = *(const v4i*)(bp + 3072); \
    As[s][0] = *(const v4i*)ap;          As[s][1] = *(const v4i*)(ap + 1024); \
    ap += ACH; bp += NDIG * 1024

#define BODY(s)                                                         \
    {                                                                   \
        v4i t0 = *(const v4i*)bp;          v4i t1 = *(const v4i*)(bp + 1024); \
        v4i t2 = *(const v4i*)(bp + 2048); v4i t3 = *(const v4i*)(bp + 3072); \
        v4i t4 = *(const v4i*)ap;          v4i t5 = *(const v4i*)(ap + 1024); \
        ap += ACH; bp += NDIG * 1024;                                   \
        MFMA_GRP(s);                                                    \
        Bs[s][0] = t0; Bs[s][1] = t1; Bs[s][2] = t2; Bs[s][3] = t3;     \
        As[s][0] = t4; As[s][1] = t5;                                   \
    }

template <int KCA, int KCP>
__global__ __launch_bounds__(256, 2) void gemm_i8_kernel(const int8_t* __restrict__ AF,
                                                         const int8_t* __restrict__ BF,
                                                         double* __restrict__ C,
                                                         double scale) {
    const int tid  = threadIdx.x;
    const int wave = tid >> 6, lane = tid & 63;
    const int i     = blockIdx.x;
    const int xcd   = i & 7;
    const int local = i >> 3;               // 0..119
    const int phase = local / 60;           // 0,1
    const int w     = local - phase * 60;   // 0..59
    const int bx    = w >> 2;               // 0..14
    const int by    = (xcd << 3) | (phase << 2) | (w & 3);   // 0..63
    const int nb  = by * 2 + (wave & 1);
    const int msb = (wave >> 1) * 2;
    const int mb0 = bx * 4 + msb;

    const int8_t* ap = AF + (((size_t)mb0 * 64 + lane) << 4);
    const int8_t* bp = BF + (((size_t)nb * KCA * NDIG) << 10) + (lane << 4);

    v16i acc[2][4] = {};
    v4i As[3][2], Bs[3][4];

    LOADC(0); LOADC(1); LOADC(2);

    for (int kc = 0; kc < KCP - 3; kc += 3) {
        BODY(0); BODY(1); BODY(2);
    }
    MFMA_GRP(0); MFMA_GRP(1); MFMA_GRP(2);

    // epilogue: C/D layout col=lane&31, row=(r&3)+8*(r>>2)+4*(lane>>5)
    const int col = lane & 31;
    const int rb  = (lane >> 5) << 2;
    const int n_g = by * 64 + (wave & 1) * 32 + col;
    #pragma unroll
    for (int s = 0; s < 2; ++s) {
        const int m_base = bx * 128 + (msb + s) * 32;
        #pragma unroll
        for (int r = 0; r < 16; ++r) {
            int row = (r & 3) + 8 * (r >> 2) + rb;
            long long v = 0;
            #pragma unroll
            for (int d = 3; d >= 0; --d) v = (v << 8) + (long long)acc[s][d][r];
            C[(size_t)(m_base + row) * HIDDEN + n_g] = (double)v * scale;
        }
    }
}

// ---------------- layer 1 LIF: f64 currents, spikes -> A-fragments ---------
__global__ __launch_bounds__(256) void lif1_kernel(const double* __restrict__ CUR,
                                                   uint8_t* __restrict__ AF,
                                                   float* __restrict__ out1) {
    int e = blockIdx.x * 256 + threadIdx.x;
    int b = e >> 12;
    int j = e & 4095;
    int kc = j >> 5;
    int lane = (b & 31) | (((j >> 4) & 1) << 5);
    size_t base = (((size_t)(kc * MB_CNT + (b >> 5)) * 64 + lane) << 4) + (j & 15);
    double v = 0.0;
    int cnt = 0;
    #pragma unroll
    for (int t = 0; t < T_STEPS; ++t) {
        double cur = CUR[(size_t)t * N1 + e];
        v = __dadd_rn(__dmul_rn(v, 0.99), cur);
        int s = (v >= 0.5) ? 1 : 0;
        cnt += s;
        v = s ? 0.0 : v;
        AF[base + (size_t)t * 2048] = (uint8_t)s;
    }
    out1[e] = (float)cnt / 30.0f;
}

// ---------------- layer 2 LIF in fp64 (unchanged, passing) -----------------
__global__ __launch_bounds__(256) void lif2_kernel(const double* __restrict__ CUR,
                                                   float* __restrict__ out2) {
    int e = blockIdx.x * 256 + threadIdx.x;
    double v = 0.0;
    int cnt = 0;
    #pragma unroll
    for (int t = 0; t < T_STEPS; ++t) {
        double cur = CUR[(size_t)t * N1 + e];
        v = __dadd_rn(__dmul_rn(v, 0.99), cur);
        int s = (v >= 0.5) ? 1 : 0;
        cnt += s;
        v = s ? 0.0 : v;
    }
    out2[e] = (float)cnt / 30.0f;
}

extern "C" void kernel_launch(void* const* d_in, const int* in_sizes, int n_in,
                              void* d_out, int out_size, void* d_ws, size_t ws_size,
                              hipStream_t stream) {
    const float* x  = (const float*)d_in[0];
    const float* W1 = (const float*)d_in[1];   // 784 x 4096
    const float* W2 = (const float*)d_in[2];   // 4096 x 4096
    float* out = (float*)d_out;
    char*  ws  = (char*)d_ws;

    // workspace (~156 MB):
    // [maxbits 256B][AF1 1.66MB][BF1 14.7MB][AF2 7.93MB][BF2 69.2MB][CURd 62.9MB]
    const size_t AF1_SZ = (size_t)KCP1 * ACH;                    // 27 chunks
    const size_t BF1_SZ = (size_t)128 * KCA1 * NDIG * 1024;      // 28 chunks alloc
    const size_t AF2_SZ = (size_t)KCP2 * ACH;                    // 129 chunks
    const size_t BF2_SZ = (size_t)128 * KCA2 * NDIG * 1024;      // 132 chunks alloc
    unsigned* maxbits = (unsigned*)ws;
    uint8_t*  AF1 = (uint8_t*)(ws + 256);
    int8_t*   BF1 = (int8_t*)(AF1 + AF1_SZ);
    uint8_t*  AF2 = (uint8_t*)(BF1 + BF1_SZ);
    int8_t*   BF2 = (int8_t*)(AF2 + AF2_SZ);
    double*   CURd = (double*)((char*)BF2 + BF2_SZ);

    float* out0 = out;
    float* out1 = out + N0;
    float* out2 = out + N0 + N1;

    hipMemsetAsync(maxbits, 0, 4, stream);
    hipMemsetAsync(AF1, 0, AF1_SZ, stream);                  // K-pad + chunks 25,26
    hipMemsetAsync(AF2 + (size_t)128 * ACH, 0, ACH, stream); // zero chunk 128
    max_kernel <<<(N0 + 255) / 256, 256, 0, stream>>>(x, maxbits);
    lif0_kernel<<<dim3(4, BATCH), 256, 0, stream>>>(x, maxbits, AF1, out0);
    digitize_kernel<<<dim3(128, KCA1 / 4), 256, 0, stream>>>(W1, BF1, INPUT_DIM, KCA1,
                                                             4294967296.0);      // 2^32
    digitize_kernel<<<dim3(128, KCA2 / 4), 256, 0, stream>>>(W2, BF2, HIDDEN, KCA2,
                                                             8589934592.0);      // 2^33
    gemm_i8_kernel<KCA1, KCP1><<<960, 256, 0, stream>>>((const int8_t*)AF1, BF1, CURd,
                                                        2.3283064365386963e-10); // 2^-32
    lif1_kernel<<<N1 / 256, 256, 0, stream>>>(CURd, AF2, out1);
    gemm_i8_kernel<KCA2, KCP2><<<960, 256, 0, stream>>>((const int8_t*)AF2, BF2, CURd,
                                                        1.1641532182693481e-10); // 2^-33
    lif2_kernel<<<N1 / 256, 256, 0, stream>>>(CURd, out2);
}